// Round 4
// baseline (299.755 us; speedup 1.0000x reference)
//
#include <hip/hip_runtime.h>

// ProtoNet: out[q][n] = -|| (xq[q]@W + b) - proto[n] ||^2
// proto[n] = (sum_{s: ys==n} xs[s]) @ W / max(cnt,1) + cnt*b/max(cnt,1)
// Per-slice fusion: out[q][c] = sum_{slices s} (2*S_s[q][c] - qn_s[q] - pn_s[c])
// where S_s = z_slice @ proto_slice^T, all slice-local inside one GEMM block.

typedef __attribute__((ext_vector_type(8))) short short8;
typedef __attribute__((ext_vector_type(4))) float floatx4;

#define S_ROWS 1024
#define F_DIM  2048
#define D_DIM  512
#define NWAY   64
#define Q_ROWS 16384

static __device__ __forceinline__ unsigned short f2bf(float f) {
  unsigned int u = __float_as_uint(f);
  u += 0x7FFF + ((u >> 16) & 1);   // RNE
  return (unsigned short)(u >> 16);
}
static __device__ __forceinline__ float bf2f(unsigned short s) {
  return __uint_as_float(((unsigned int)s) << 16);
}

// async global->LDS, 16B per lane. LDS dest = wave-uniform base + lane*16.
static __device__ __forceinline__ void load_lds16(const unsigned short* g, unsigned short* l) {
  __builtin_amdgcn_global_load_lds((const __attribute__((address_space(1))) unsigned int*)g,
                                   (__attribute__((address_space(3))) unsigned int*)l,
                                   16, 0, 0);
}

// ---- K0a: transpose W f32 [2048][512] -> Wt bf16 [512][2048];
//      zero out[16384*64] and proto_acc[64*512] ----
__global__ __launch_bounds__(256) void k0_transpose(const float* __restrict__ W,
                                                    unsigned short* __restrict__ Wt,
                                                    float* __restrict__ outz,
                                                    float* __restrict__ proto_acc) {
  __shared__ unsigned short t[64][65];
  int bx = blockIdx.x;
  int f0 = (bx >> 3) << 6;   // 32 f-tiles
  int d0 = (bx & 7) << 6;    // 8 d-tiles
  for (int j = 0; j < 16; j++) {
    int lin = j * 256 + threadIdx.x;
    int fl = lin >> 6, dl = lin & 63;
    t[fl][dl] = f2bf(W[(size_t)(f0 + fl) * 512 + d0 + dl]);
  }
  __syncthreads();
  for (int j = 0; j < 16; j++) {
    int lin = j * 256 + threadIdx.x;
    int dl = lin >> 6, fl = lin & 63;
    Wt[(size_t)(d0 + dl) * 2048 + f0 + fl] = t[fl][dl];
  }
  int tid = threadIdx.x;
  float4 zz = {0.f, 0.f, 0.f, 0.f};
#pragma unroll
  for (int p = 0; p < 4; p++)
    *(float4*)&outz[(size_t)bx * 4096 + p * 1024 + tid * 4] = zz;
  if (tid < 128) proto_acc[bx * 128 + tid] = 0.f;
}

// ---- K0b: bin support indices by class via LDS atomics (single block) ----
__global__ __launch_bounds__(256) void k0_sort(const int* __restrict__ ys,
                                               int* __restrict__ order,
                                               int* __restrict__ starts,
                                               float* __restrict__ counts) {
  __shared__ int cnt[NWAY];
  __shared__ int st[NWAY + 1];
  __shared__ int wp[NWAY];
  int tid = threadIdx.x;
  if (tid < NWAY) cnt[tid] = 0;
  __syncthreads();
  for (int j = tid; j < S_ROWS; j += 256) atomicAdd(&cnt[ys[j]], 1);
  __syncthreads();
  if (tid == 0) {
    int a = 0;
    for (int c = 0; c < NWAY; c++) { st[c] = a; wp[c] = a; a += cnt[c]; }
    st[NWAY] = a;
  }
  __syncthreads();
  for (int j = tid; j < S_ROWS; j += 256) {
    int c = ys[j];
    int p = atomicAdd(&wp[c], 1);
    order[p] = j;
  }
  if (tid < NWAY) counts[tid] = (float)cnt[tid];
  if (tid < NWAY + 1) starts[tid] = st[tid];
}

// ---- K1: class sums. grid = 64 classes x 2 f-tiles; float4 per thread ----
__global__ __launch_bounds__(256) void k1_csum(const float* __restrict__ xs,
                                               const int* __restrict__ order,
                                               const int* __restrict__ starts,
                                               float* __restrict__ csum) {
  __shared__ int lord[S_ROWS];
  int c = blockIdx.x >> 1;
  int tid = threadIdx.x;
  int s = starts[c], e = starts[c + 1];
  int len = e - s;
  for (int j = tid; j < len; j += 256) lord[j] = order[s + j];
  __syncthreads();
  int f0 = (blockIdx.x & 1) * 1024 + tid * 4;
  float4 a = {0.f, 0.f, 0.f, 0.f};
  for (int i = 0; i < len; i++) {
    float4 v = *(const float4*)&xs[(size_t)lord[i] * F_DIM + f0];
    a.x += v.x; a.y += v.y; a.z += v.z; a.w += v.w;
  }
  *(float4*)&csum[(size_t)c * F_DIM + f0] = a;
}

// ---- K2: partial proto: grid = 64 classes x 2 d-halves x 8 f-chunks = 1024 blocks ----
__global__ __launch_bounds__(256) void k2_proto(const float* __restrict__ W,
                                               const float* __restrict__ csum,
                                               float* __restrict__ proto_acc) {
  __shared__ float cs[256];
  int bx = blockIdx.x;
  int c = bx >> 4;
  int dh = ((bx >> 3) & 1) * 256;
  int fc = (bx & 7) * 256;
  int tid = threadIdx.x;
  cs[tid] = csum[(size_t)c * F_DIM + fc + tid];
  __syncthreads();
  float a0 = 0.f;
#pragma unroll 8
  for (int f = 0; f < 256; f++)
    a0 += cs[f] * W[(size_t)(fc + f) * 512 + dh + tid];
  atomicAdd(&proto_acc[c * 512 + dh + tid], a0);
}

// ---- K2b: finalize proto: scale, +bias, bf16, per-128-slice pnorm_part[4][64] ----
__global__ __launch_bounds__(256) void k2b_finalize(const float* __restrict__ proto_acc,
                                                    const float* __restrict__ b,
                                                    const float* __restrict__ counts,
                                                    unsigned short* __restrict__ proto_bf,
                                                    float* __restrict__ pnorm_part) {
  __shared__ float red[256];
  int n = blockIdx.x, tid = threadIdx.x;
  float cntv = counts[n];
  float inv = 1.f / fmaxf(cntv, 1.f);
  float qsq[2];
#pragma unroll
  for (int h = 0; h < 2; h++) {
    int d = h * 256 + tid;
    float p = (proto_acc[n * 512 + d] + cntv * b[d]) * inv;
    unsigned short hh = f2bf(p);
    proto_bf[(size_t)n * 512 + d] = hh;
    float q = bf2f(hh);
    qsq[h] = q * q;
  }
#pragma unroll
  for (int h = 0; h < 2; h++) {
    __syncthreads();
    red[tid] = qsq[h];
    __syncthreads();
    for (int s = 64; s > 0; s >>= 1) {
      if ((tid & 127) < s) red[tid] += red[tid + s];
      __syncthreads();
    }
    if (tid == 0) pnorm_part[(h * 2 + 0) * 64 + n] = red[0];
    if (tid == 128) pnorm_part[(h * 2 + 1) * 64 + n] = red[128];
  }
}

// ---- Kcvt: xq f32 -> bf16, 8 elems/thread ----
__global__ __launch_bounds__(256) void k_cvt(const float* __restrict__ xq,
                                             unsigned short* __restrict__ xqb) {
  size_t i = ((size_t)blockIdx.x * 256 + threadIdx.x) * 8;
  float4 v0 = *(const float4*)&xq[i];
  float4 v1 = *(const float4*)&xq[i + 4];
  ushort4 w0, w1;
  w0.x = f2bf(v0.x); w0.y = f2bf(v0.y); w0.z = f2bf(v0.z); w0.w = f2bf(v0.w);
  w1.x = f2bf(v1.x); w1.y = f2bf(v1.y); w1.z = f2bf(v1.z); w1.w = f2bf(v1.w);
  *(ushort4*)&xqb[i] = w0;
  *(ushort4*)&xqb[i + 4] = w1;
}

// ---- K3 fused: z-tile GEMM (128x128xK2048) + fused distance epilogue.
//      Epilogue: z -> LDS (bf16) + slice row-norms; S = z @ proto_slice^T via MFMA;
//      atomicAdd(2S - qn - pn) into out. ----
#define ZS_LD 136   // padded leading dim (halfs): bank step 4 -> conflict-free b128 reads
__global__ __launch_bounds__(256) void k3_fused(const unsigned short* __restrict__ xqb,
                                                const unsigned short* __restrict__ Wt,
                                                const float* __restrict__ b,
                                                const unsigned short* __restrict__ proto_bf,
                                                const float* __restrict__ pnorm_part,
                                                float* __restrict__ out) {
  // union LDS: main loop lA(8K)+lB(8K); epilogue zs(34816)+pb(17408)+qnf(512)+pnl(256)
  __shared__ __align__(16) char smem[53248];
  unsigned short* lA = (unsigned short*)smem;
  unsigned short* lB = (unsigned short*)(smem + 8192);
  unsigned short* zs = (unsigned short*)smem;
  unsigned short* pb = (unsigned short*)(smem + 34816);
  float* qnf = (float*)(smem + 52224);
  float* pnl = (float*)(smem + 52736);

  int tid = threadIdx.x;
  int bx = blockIdx.x;
  // XCD swizzle: 4 n-slices of one m-strip land on the same XCD (round-robin bx%8)
  int xcd = bx & 7;
  int g = bx >> 3;
  int m0 = (xcd * 16 + (g & 15)) * 128;
  int n0 = (g >> 4) * 128;
  int slice = g >> 4;

  int wave = tid >> 6, lane = tid & 63;
  int wm = (wave & 1) * 64, wn = (wave >> 1) * 64;
  int lrow = lane & 15, lquad = lane >> 4;

  floatx4 acc[4][4];
#pragma unroll
  for (int i = 0; i < 4; i++)
#pragma unroll
    for (int j = 0; j < 4; j++) acc[i][j] = (floatx4){0.f, 0.f, 0.f, 0.f};

  int c0 = wave * 64 + lane;

  for (int k0 = 0; k0 < F_DIM; k0 += 32) {
#pragma unroll
    for (int i = 0; i < 2; i++) {
      int c = i * 256 + c0;
      int row = c >> 2, k8 = (c & 3) * 8;
      load_lds16(&xqb[(size_t)(m0 + row) * F_DIM + k0 + k8],
                 &lA[(size_t)(i * 256 + wave * 64) * 8]);
      load_lds16(&Wt[(size_t)(n0 + row) * F_DIM + k0 + k8],
                 &lB[(size_t)(i * 256 + wave * 64) * 8]);
    }
    __syncthreads();
    short8 af[4], bfr[4];
#pragma unroll
    for (int i = 0; i < 4; i++) af[i] = *(const short8*)&lA[(wm + i * 16 + lrow) * 32 + lquad * 8];
#pragma unroll
    for (int j = 0; j < 4; j++) bfr[j] = *(const short8*)&lB[(wn + j * 16 + lrow) * 32 + lquad * 8];
#pragma unroll
    for (int i = 0; i < 4; i++)
#pragma unroll
      for (int j = 0; j < 4; j++)
        acc[i][j] = __builtin_amdgcn_mfma_f32_16x16x32_bf16(af[i], bfr[j], acc[i][j], 0, 0, 0);
    __syncthreads();
  }

  // ---- epilogue phase 1: init qn, z -> LDS bf16, slice row-norms ----
  if (tid < 128) qnf[tid] = 0.f;
  if (tid < 64) pnl[tid] = pnorm_part[slice * 64 + tid];
  __syncthreads();

#pragma unroll
  for (int i = 0; i < 4; i++) {
    float rn[4] = {0.f, 0.f, 0.f, 0.f};
#pragma unroll
    for (int j = 0; j < 4; j++) {
      int ld = wn + j * 16 + lrow;          // local d (0..127)
      float bb = b[n0 + ld];
#pragma unroll
      for (int r = 0; r < 4; r++) {
        int rl = wm + i * 16 + lquad * 4 + r;  // local q (0..127)
        float v = acc[i][j][r] + bb;
        unsigned short h = f2bf(v);
        zs[rl * ZS_LD + ld] = h;
        float vq = bf2f(h);
        rn[r] += vq * vq;
      }
    }
#pragma unroll
    for (int r = 0; r < 4; r++) {
      float s = rn[r];
      s += __shfl_xor(s, 1, 16);
      s += __shfl_xor(s, 2, 16);
      s += __shfl_xor(s, 4, 16);
      s += __shfl_xor(s, 8, 16);
      if (lrow == 0) atomicAdd(&qnf[wm + i * 16 + lquad * 4 + r], s);
    }
  }

  // ---- phase 2: proto slice -> LDS (64 rows x 128 halfs, padded) ----
  // 1024 chunks of 16B; 4 per thread. chunk ch: row=ch>>4, ld8=(ch&15)*8
#pragma unroll
  for (int p = 0; p < 4; p++) {
    int ch = p * 256 + tid;
    int row = ch >> 4, l8 = (ch & 15) * 8;
    *(short8*)&pb[row * ZS_LD + l8] =
        *(const short8*)&proto_bf[(size_t)row * 512 + n0 + l8];
  }
  __syncthreads();

  // ---- phase 3: S = zs @ pb^T (128x64x128), out partial ----
  floatx4 acc2[2][4];
#pragma unroll
  for (int i = 0; i < 2; i++)
#pragma unroll
    for (int j = 0; j < 4; j++) acc2[i][j] = (floatx4){0.f, 0.f, 0.f, 0.f};

#pragma unroll
  for (int ks = 0; ks < 4; ks++) {
    short8 af2[2], bf2[4];
#pragma unroll
    for (int i = 0; i < 2; i++)
      af2[i] = *(const short8*)&zs[(wave * 32 + i * 16 + lrow) * ZS_LD + ks * 32 + lquad * 8];
#pragma unroll
    for (int j = 0; j < 4; j++)
      bf2[j] = *(const short8*)&pb[(j * 16 + lrow) * ZS_LD + ks * 32 + lquad * 8];
#pragma unroll
    for (int i = 0; i < 2; i++)
#pragma unroll
      for (int j = 0; j < 4; j++)
        acc2[i][j] = __builtin_amdgcn_mfma_f32_16x16x32_bf16(af2[i], bf2[j], acc2[i][j], 0, 0, 0);
  }

#pragma unroll
  for (int i = 0; i < 2; i++) {
#pragma unroll
    for (int j = 0; j < 4; j++) {
      int c = j * 16 + lrow;
      float pn = pnl[c];
#pragma unroll
      for (int r = 0; r < 4; r++) {
        int ql = wave * 32 + i * 16 + lquad * 4 + r;
        float val = 2.f * acc2[i][j][r] - qnf[ql] - pn;
        atomicAdd(&out[(size_t)(m0 + ql) * 64 + c], val);
      }
    }
  }
}

extern "C" void kernel_launch(void* const* d_in, const int* in_sizes, int n_in,
                              void* d_out, int out_size, void* d_ws, size_t ws_size,
                              hipStream_t stream) {
  const float* xs = (const float*)d_in[0];
  const int* ys = (const int*)d_in[1];
  const float* xq = (const float*)d_in[2];
  const float* W = (const float*)d_in[3];
  const float* b = (const float*)d_in[4];
  float* out = (float*)d_out;
  char* ws = (char*)d_ws;

  size_t off = 0;
  auto take = [&](size_t bytes) -> char* {
    char* r = ws + off;
    off += (bytes + 255) & ~(size_t)255;
    return r;
  };
  unsigned short* Wt = (unsigned short*)take((size_t)D_DIM * F_DIM * 2);
  float* csum = (float*)take((size_t)NWAY * F_DIM * 4);
  float* proto_acc = (float*)take((size_t)NWAY * D_DIM * 4);
  unsigned short* proto_bf = (unsigned short*)take((size_t)NWAY * D_DIM * 2);
  float* counts = (float*)take(NWAY * 4);
  float* pnorm_part = (float*)take(4 * NWAY * 4);
  int* order = (int*)take(S_ROWS * 4);
  int* starts = (int*)take((NWAY + 1) * 4);
  unsigned short* xqb = (unsigned short*)take((size_t)Q_ROWS * F_DIM * 2);

  k0_transpose<<<256, 256, 0, stream>>>(W, Wt, out, proto_acc);
  k0_sort<<<1, 256, 0, stream>>>(ys, order, starts, counts);
  k1_csum<<<128, 256, 0, stream>>>(xs, order, starts, csum);
  k2_proto<<<1024, 256, 0, stream>>>(W, csum, proto_acc);
  k2b_finalize<<<64, 256, 0, stream>>>(proto_acc, b, counts, proto_bf, pnorm_part);
  k_cvt<<<(Q_ROWS * F_DIM) / (256 * 8), 256, 0, stream>>>(xq, xqb);
  k3_fused<<<512, 256, 0, stream>>>(xqb, Wt, b, proto_bf, pnorm_part, out);
}

// Round 5
// 291.562 us; speedup vs baseline: 1.0281x; 1.0281x over previous
//
#include <hip/hip_runtime.h>

// ProtoNet: out[q][n] = -|| (xq[q]@W + b) - proto[n] ||^2
// proto[n] = (sum_{s: ys==n} xs[s]) @ W / max(cnt,1) + cnt*b/max(cnt,1)
// Per-slice fusion: out[q][c] = sum_{slices s} (2*S_s[q][c] - qn_s[q] - pn_s[c])
// k3 reads xq f32 directly; A-tile converted in-register (round-half-up + v_perm
// pack = 3 VALU / 2 elems) -- kills the 192 MB k_cvt round-trip.

typedef __attribute__((ext_vector_type(8))) short short8;
typedef __attribute__((ext_vector_type(4))) float floatx4;

#define S_ROWS 1024
#define F_DIM  2048
#define D_DIM  512
#define NWAY   64
#define Q_ROWS 16384

static __device__ __forceinline__ unsigned short f2bf(float f) {
  unsigned int u = __float_as_uint(f);
  u += 0x7FFF + ((u >> 16) & 1);   // RNE
  return (unsigned short)(u >> 16);
}
static __device__ __forceinline__ float bf2f(unsigned short s) {
  return __uint_as_float(((unsigned int)s) << 16);
}
// pack two floats -> two bf16 (round-half-up; ties-only deviation from RNE)
static __device__ __forceinline__ unsigned int pack_bf2(float x, float y) {
  unsigned int ux = __float_as_uint(x) + 0x8000u;
  unsigned int uy = __float_as_uint(y) + 0x8000u;
  return __builtin_amdgcn_perm(uy, ux, 0x07060302u);  // hi16(uy)<<16 | hi16(ux)
}

// async global->LDS, 16B per lane. LDS dest = wave-uniform base + lane*16.
static __device__ __forceinline__ void load_lds16(const unsigned short* g, unsigned short* l) {
  __builtin_amdgcn_global_load_lds((const __attribute__((address_space(1))) unsigned int*)g,
                                   (__attribute__((address_space(3))) unsigned int*)l,
                                   16, 0, 0);
}

// ---- Kprep (257 blocks): blocks 0..255 transpose W f32 [2048][512] -> Wt bf16
//      [512][2048] + zero out/proto_acc; block 256 bins support ids by class ----
__global__ __launch_bounds__(256) void k_prep(const float* __restrict__ W,
                                              unsigned short* __restrict__ Wt,
                                              float* __restrict__ outz,
                                              float* __restrict__ proto_acc,
                                              const int* __restrict__ ys,
                                              int* __restrict__ order,
                                              int* __restrict__ starts,
                                              float* __restrict__ counts) {
  __shared__ unsigned short t[64][65];
  __shared__ int cnt[NWAY];
  __shared__ int st[NWAY + 1];
  __shared__ int wp[NWAY];
  int bx = blockIdx.x;
  int tid = threadIdx.x;
  if (bx < 256) {
    int f0 = (bx >> 3) << 6;   // 32 f-tiles
    int d0 = (bx & 7) << 6;    // 8 d-tiles
    for (int j = 0; j < 16; j++) {
      int lin = j * 256 + tid;
      int fl = lin >> 6, dl = lin & 63;
      t[fl][dl] = f2bf(W[(size_t)(f0 + fl) * 512 + d0 + dl]);
    }
    __syncthreads();
    for (int j = 0; j < 16; j++) {
      int lin = j * 256 + tid;
      int dl = lin >> 6, fl = lin & 63;
      Wt[(size_t)(d0 + dl) * 2048 + f0 + fl] = t[fl][dl];
    }
    float4 zz = {0.f, 0.f, 0.f, 0.f};
#pragma unroll
    for (int p = 0; p < 4; p++)
      *(float4*)&outz[(size_t)bx * 4096 + p * 1024 + tid * 4] = zz;
    if (tid < 128) proto_acc[bx * 128 + tid] = 0.f;
  } else {
    if (tid < NWAY) cnt[tid] = 0;
    __syncthreads();
    for (int j = tid; j < S_ROWS; j += 256) atomicAdd(&cnt[ys[j]], 1);
    __syncthreads();
    if (tid == 0) {
      int a = 0;
      for (int c = 0; c < NWAY; c++) { st[c] = a; wp[c] = a; a += cnt[c]; }
      st[NWAY] = a;
    }
    __syncthreads();
    for (int j = tid; j < S_ROWS; j += 256) {
      int c = ys[j];
      int p = atomicAdd(&wp[c], 1);
      order[p] = j;
    }
    if (tid < NWAY) counts[tid] = (float)cnt[tid];
    if (tid < NWAY + 1) starts[tid] = st[tid];
  }
}

// ---- K1: class sums. grid = 64 classes x 2 f-tiles; float4 per thread ----
__global__ __launch_bounds__(256) void k1_csum(const float* __restrict__ xs,
                                               const int* __restrict__ order,
                                               const int* __restrict__ starts,
                                               float* __restrict__ csum) {
  __shared__ int lord[S_ROWS];
  int c = blockIdx.x >> 1;
  int tid = threadIdx.x;
  int s = starts[c], e = starts[c + 1];
  int len = e - s;
  for (int j = tid; j < len; j += 256) lord[j] = order[s + j];
  __syncthreads();
  int f0 = (blockIdx.x & 1) * 1024 + tid * 4;
  float4 a = {0.f, 0.f, 0.f, 0.f};
  for (int i = 0; i < len; i++) {
    float4 v = *(const float4*)&xs[(size_t)lord[i] * F_DIM + f0];
    a.x += v.x; a.y += v.y; a.z += v.z; a.w += v.w;
  }
  *(float4*)&csum[(size_t)c * F_DIM + f0] = a;
}

// ---- K2: partial proto: grid = 64 classes x 2 d-halves x 8 f-chunks = 1024 blocks ----
__global__ __launch_bounds__(256) void k2_proto(const float* __restrict__ W,
                                               const float* __restrict__ csum,
                                               float* __restrict__ proto_acc) {
  __shared__ float cs[256];
  int bx = blockIdx.x;
  int c = bx >> 4;
  int dh = ((bx >> 3) & 1) * 256;
  int fc = (bx & 7) * 256;
  int tid = threadIdx.x;
  cs[tid] = csum[(size_t)c * F_DIM + fc + tid];
  __syncthreads();
  float a0 = 0.f;
#pragma unroll 8
  for (int f = 0; f < 256; f++)
    a0 += cs[f] * W[(size_t)(fc + f) * 512 + dh + tid];
  atomicAdd(&proto_acc[c * 512 + dh + tid], a0);
}

// ---- K2b: finalize proto: scale, +bias, bf16, per-128-slice pnorm_part[4][64] ----
__global__ __launch_bounds__(256) void k2b_finalize(const float* __restrict__ proto_acc,
                                                    const float* __restrict__ b,
                                                    const float* __restrict__ counts,
                                                    unsigned short* __restrict__ proto_bf,
                                                    float* __restrict__ pnorm_part) {
  __shared__ float red[256];
  int n = blockIdx.x, tid = threadIdx.x;
  float cntv = counts[n];
  float inv = 1.f / fmaxf(cntv, 1.f);
  float qsq[2];
#pragma unroll
  for (int h = 0; h < 2; h++) {
    int d = h * 256 + tid;
    float p = (proto_acc[n * 512 + d] + cntv * b[d]) * inv;
    unsigned short hh = f2bf(p);
    proto_bf[(size_t)n * 512 + d] = hh;
    float q = bf2f(hh);
    qsq[h] = q * q;
  }
#pragma unroll
  for (int h = 0; h < 2; h++) {
    __syncthreads();
    red[tid] = qsq[h];
    __syncthreads();
    for (int s = 64; s > 0; s >>= 1) {
      if ((tid & 127) < s) red[tid] += red[tid + s];
      __syncthreads();
    }
    if (tid == 0) pnorm_part[(h * 2 + 0) * 64 + n] = red[0];
    if (tid == 128) pnorm_part[(h * 2 + 1) * 64 + n] = red[128];
  }
}

// ---- K3 fused: z-tile GEMM (128x128xK2048, A = f32 xq converted in-register)
//      + fused distance epilogue (z->LDS, row-norms, S = z@proto^T, atomic out) ----
#define ZS_LD 136   // padded leading dim (halfs) for epilogue tiles
__global__ __launch_bounds__(256) void k3_fused(const float* __restrict__ xq,
                                                const unsigned short* __restrict__ Wt,
                                                const float* __restrict__ b,
                                                const unsigned short* __restrict__ proto_bf,
                                                const float* __restrict__ pnorm_part,
                                                float* __restrict__ out) {
  // union LDS: main loop lA(8K)+lB(8K); epilogue zs(34816)+pb(17408)+qnf(512)+pnl(256)
  __shared__ __align__(16) char smem[53248];
  unsigned short* lA = (unsigned short*)smem;
  unsigned short* lB = (unsigned short*)(smem + 8192);
  unsigned short* zs = (unsigned short*)smem;
  unsigned short* pb = (unsigned short*)(smem + 34816);
  float* qnf = (float*)(smem + 52224);
  float* pnl = (float*)(smem + 52736);

  int tid = threadIdx.x;
  int bx = blockIdx.x;
  // XCD swizzle: 4 n-slices of one m-strip land on the same XCD (round-robin bx%8)
  int xcd = bx & 7;
  int g = bx >> 3;
  int m0 = (xcd * 16 + (g & 15)) * 128;
  int n0 = (g >> 4) * 128;
  int slice = g >> 4;

  int wave = tid >> 6, lane = tid & 63;
  int wm = (wave & 1) * 64, wn = (wave >> 1) * 64;
  int lrow = lane & 15, lquad = lane >> 4;

  floatx4 acc[4][4];
#pragma unroll
  for (int i = 0; i < 4; i++)
#pragma unroll
    for (int j = 0; j < 4; j++) acc[i][j] = (floatx4){0.f, 0.f, 0.f, 0.f};

  int c0 = wave * 64 + lane;
  // A-staging geometry: thread covers 16 consecutive k of one row
  int arow = tid >> 1, akh = (tid & 1) * 16;
  const float* agp = &xq[(size_t)(m0 + arow) * F_DIM + akh];
  unsigned int* lAu = (unsigned int*)&lA[arow * 32 + akh];

  for (int k0 = 0; k0 < F_DIM; k0 += 32) {
    // A: f32 global -> VGPR (compiler can hoist these across the trailing barrier)
    float4 va0 = *(const float4*)(agp + k0);
    float4 va1 = *(const float4*)(agp + k0 + 4);
    float4 va2 = *(const float4*)(agp + k0 + 8);
    float4 va3 = *(const float4*)(agp + k0 + 12);
    // B: async global->LDS
#pragma unroll
    for (int i = 0; i < 2; i++) {
      int c = i * 256 + c0;
      int row = c >> 2, k8 = (c & 3) * 8;
      load_lds16(&Wt[(size_t)(n0 + row) * F_DIM + k0 + k8],
                 &lB[(size_t)(i * 256 + wave * 64) * 8]);
    }
    // pack A to bf16 pairs (3 VALU / 2 elems)
    uint4 w0, w1;
    w0.x = pack_bf2(va0.x, va0.y); w0.y = pack_bf2(va0.z, va0.w);
    w0.z = pack_bf2(va1.x, va1.y); w0.w = pack_bf2(va1.z, va1.w);
    w1.x = pack_bf2(va2.x, va2.y); w1.y = pack_bf2(va2.z, va2.w);
    w1.z = pack_bf2(va3.x, va3.y); w1.w = pack_bf2(va3.z, va3.w);
    *(uint4*)lAu = w0;
    *(uint4*)(lAu + 4) = w1;
    __syncthreads();
    short8 af[4], bfr[4];
#pragma unroll
    for (int i = 0; i < 4; i++) af[i] = *(const short8*)&lA[(wm + i * 16 + lrow) * 32 + lquad * 8];
#pragma unroll
    for (int j = 0; j < 4; j++) bfr[j] = *(const short8*)&lB[(wn + j * 16 + lrow) * 32 + lquad * 8];
#pragma unroll
    for (int i = 0; i < 4; i++)
#pragma unroll
      for (int j = 0; j < 4; j++)
        acc[i][j] = __builtin_amdgcn_mfma_f32_16x16x32_bf16(af[i], bfr[j], acc[i][j], 0, 0, 0);
    __syncthreads();
  }

  // ---- epilogue phase 1: init qn, z -> LDS bf16, slice row-norms ----
  if (tid < 128) qnf[tid] = 0.f;
  if (tid < 64) pnl[tid] = pnorm_part[slice * 64 + tid];
  __syncthreads();

#pragma unroll
  for (int i = 0; i < 4; i++) {
    float rn[4] = {0.f, 0.f, 0.f, 0.f};
#pragma unroll
    for (int j = 0; j < 4; j++) {
      int ld = wn + j * 16 + lrow;          // local d (0..127)
      float bb = b[n0 + ld];
#pragma unroll
      for (int r = 0; r < 4; r++) {
        int rl = wm + i * 16 + lquad * 4 + r;  // local q (0..127)
        float v = acc[i][j][r] + bb;
        unsigned short h = f2bf(v);
        zs[rl * ZS_LD + ld] = h;
        float vq = bf2f(h);
        rn[r] += vq * vq;
      }
    }
#pragma unroll
    for (int r = 0; r < 4; r++) {
      float s = rn[r];
      s += __shfl_xor(s, 1, 16);
      s += __shfl_xor(s, 2, 16);
      s += __shfl_xor(s, 4, 16);
      s += __shfl_xor(s, 8, 16);
      if (lrow == 0) atomicAdd(&qnf[wm + i * 16 + lquad * 4 + r], s);
    }
  }

  // ---- phase 2: proto slice -> LDS (64 rows x 128 halfs, padded) ----
#pragma unroll
  for (int p = 0; p < 4; p++) {
    int ch = p * 256 + tid;
    int row = ch >> 4, l8 = (ch & 15) * 8;
    *(short8*)&pb[row * ZS_LD + l8] =
        *(const short8*)&proto_bf[(size_t)row * 512 + n0 + l8];
  }
  __syncthreads();

  // ---- phase 3: S = zs @ pb^T (128x64x128), out partial ----
  floatx4 acc2[2][4];
#pragma unroll
  for (int i = 0; i < 2; i++)
#pragma unroll
    for (int j = 0; j < 4; j++) acc2[i][j] = (floatx4){0.f, 0.f, 0.f, 0.f};

#pragma unroll
  for (int ks = 0; ks < 4; ks++) {
    short8 af2[2], bf2r[4];
#pragma unroll
    for (int i = 0; i < 2; i++)
      af2[i] = *(const short8*)&zs[(wave * 32 + i * 16 + lrow) * ZS_LD + ks * 32 + lquad * 8];
#pragma unroll
    for (int j = 0; j < 4; j++)
      bf2r[j] = *(const short8*)&pb[(j * 16 + lrow) * ZS_LD + ks * 32 + lquad * 8];
#pragma unroll
    for (int i = 0; i < 2; i++)
#pragma unroll
      for (int j = 0; j < 4; j++)
        acc2[i][j] = __builtin_amdgcn_mfma_f32_16x16x32_bf16(af2[i], bf2r[j], acc2[i][j], 0, 0, 0);
  }

#pragma unroll
  for (int i = 0; i < 2; i++) {
#pragma unroll
    for (int j = 0; j < 4; j++) {
      int c = j * 16 + lrow;
      float pn = pnl[c];
#pragma unroll
      for (int r = 0; r < 4; r++) {
        int ql = wave * 32 + i * 16 + lquad * 4 + r;
        float val = 2.f * acc2[i][j][r] - qnf[ql] - pn;
        atomicAdd(&out[(size_t)(m0 + ql) * 64 + c], val);
      }
    }
  }
}

extern "C" void kernel_launch(void* const* d_in, const int* in_sizes, int n_in,
                              void* d_out, int out_size, void* d_ws, size_t ws_size,
                              hipStream_t stream) {
  const float* xs = (const float*)d_in[0];
  const int* ys = (const int*)d_in[1];
  const float* xq = (const float*)d_in[2];
  const float* W = (const float*)d_in[3];
  const float* b = (const float*)d_in[4];
  float* out = (float*)d_out;
  char* ws = (char*)d_ws;

  size_t off = 0;
  auto take = [&](size_t bytes) -> char* {
    char* r = ws + off;
    off += (bytes + 255) & ~(size_t)255;
    return r;
  };
  unsigned short* Wt = (unsigned short*)take((size_t)D_DIM * F_DIM * 2);
  float* csum = (float*)take((size_t)NWAY * F_DIM * 4);
  float* proto_acc = (float*)take((size_t)NWAY * D_DIM * 4);
  unsigned short* proto_bf = (unsigned short*)take((size_t)NWAY * D_DIM * 2);
  float* counts = (float*)take(NWAY * 4);
  float* pnorm_part = (float*)take(4 * NWAY * 4);
  int* order = (int*)take(S_ROWS * 4);
  int* starts = (int*)take((NWAY + 1) * 4);

  k_prep<<<257, 256, 0, stream>>>(W, Wt, out, proto_acc, ys, order, starts, counts);
  k1_csum<<<128, 256, 0, stream>>>(xs, order, starts, csum);
  k2_proto<<<1024, 256, 0, stream>>>(W, csum, proto_acc);
  k2b_finalize<<<64, 256, 0, stream>>>(proto_acc, b, counts, proto_bf, pnorm_part);
  k3_fused<<<512, 256, 0, stream>>>(xq, Wt, b, proto_bf, pnorm_part, out);
}

// Round 6
// 271.682 us; speedup vs baseline: 1.1033x; 1.0732x over previous
//
#include <hip/hip_runtime.h>

// ProtoNet: out[q][n] = -|| (xq[q]@W + b) - proto[n] ||^2
// proto[n] = (sum_{s: ys==n} xs[s]) @ W / max(cnt,1) + cnt*b/max(cnt,1)
// Per-slice fusion: out[q][c] = sum_{slices s} (2*S_s[q][c] - qn_s[q] - pn_s[c])
// k3: BK=64 (2 panels of 128x32 halfs per barrier), A converted in-register with
// chunk-contiguous LDS writes (conflict-free), B via global_load_lds width-16.

typedef __attribute__((ext_vector_type(8))) short short8;
typedef __attribute__((ext_vector_type(4))) float floatx4;

#define S_ROWS 1024
#define F_DIM  2048
#define D_DIM  512
#define NWAY   64
#define Q_ROWS 16384

static __device__ __forceinline__ unsigned short f2bf(float f) {
  unsigned int u = __float_as_uint(f);
  u += 0x7FFF + ((u >> 16) & 1);   // RNE
  return (unsigned short)(u >> 16);
}
static __device__ __forceinline__ float bf2f(unsigned short s) {
  return __uint_as_float(((unsigned int)s) << 16);
}
// pack two floats -> two bf16 (round-half-up; ties-only deviation from RNE)
static __device__ __forceinline__ unsigned int pack_bf2(float x, float y) {
  unsigned int ux = __float_as_uint(x) + 0x8000u;
  unsigned int uy = __float_as_uint(y) + 0x8000u;
  return __builtin_amdgcn_perm(uy, ux, 0x07060302u);  // hi16(uy)<<16 | hi16(ux)
}

// async global->LDS, 16B per lane. LDS dest = wave-uniform base + lane*16.
static __device__ __forceinline__ void load_lds16(const unsigned short* g, unsigned short* l) {
  __builtin_amdgcn_global_load_lds((const __attribute__((address_space(1))) unsigned int*)g,
                                   (__attribute__((address_space(3))) unsigned int*)l,
                                   16, 0, 0);
}

// ---- Kprep (257 blocks): blocks 0..255 transpose W f32 [2048][512] -> Wt bf16
//      [512][2048] + zero out/proto_acc; block 256 bins support ids by class ----
__global__ __launch_bounds__(256) void k_prep(const float* __restrict__ W,
                                              unsigned short* __restrict__ Wt,
                                              float* __restrict__ outz,
                                              float* __restrict__ proto_acc,
                                              const int* __restrict__ ys,
                                              int* __restrict__ order,
                                              int* __restrict__ starts,
                                              float* __restrict__ counts) {
  __shared__ unsigned short t[64][65];
  __shared__ int cnt[NWAY];
  __shared__ int st[NWAY + 1];
  __shared__ int wp[NWAY];
  int bx = blockIdx.x;
  int tid = threadIdx.x;
  if (bx < 256) {
    int f0 = (bx >> 3) << 6;   // 32 f-tiles
    int d0 = (bx & 7) << 6;    // 8 d-tiles
    for (int j = 0; j < 16; j++) {
      int lin = j * 256 + tid;
      int fl = lin >> 6, dl = lin & 63;
      t[fl][dl] = f2bf(W[(size_t)(f0 + fl) * 512 + d0 + dl]);
    }
    __syncthreads();
    for (int j = 0; j < 16; j++) {
      int lin = j * 256 + tid;
      int dl = lin >> 6, fl = lin & 63;
      Wt[(size_t)(d0 + dl) * 2048 + f0 + fl] = t[fl][dl];
    }
    float4 zz = {0.f, 0.f, 0.f, 0.f};
#pragma unroll
    for (int p = 0; p < 4; p++)
      *(float4*)&outz[(size_t)bx * 4096 + p * 1024 + tid * 4] = zz;
    if (tid < 128) proto_acc[bx * 128 + tid] = 0.f;
  } else {
    if (tid < NWAY) cnt[tid] = 0;
    __syncthreads();
    for (int j = tid; j < S_ROWS; j += 256) atomicAdd(&cnt[ys[j]], 1);
    __syncthreads();
    if (tid == 0) {
      int a = 0;
      for (int c = 0; c < NWAY; c++) { st[c] = a; wp[c] = a; a += cnt[c]; }
      st[NWAY] = a;
    }
    __syncthreads();
    for (int j = tid; j < S_ROWS; j += 256) {
      int c = ys[j];
      int p = atomicAdd(&wp[c], 1);
      order[p] = j;
    }
    if (tid < NWAY) counts[tid] = (float)cnt[tid];
    if (tid < NWAY + 1) starts[tid] = st[tid];
  }
}

// ---- K1: class sums. grid = 64 classes x 2 f-tiles; float4 per thread ----
__global__ __launch_bounds__(256) void k1_csum(const float* __restrict__ xs,
                                               const int* __restrict__ order,
                                               const int* __restrict__ starts,
                                               float* __restrict__ csum) {
  __shared__ int lord[S_ROWS];
  int c = blockIdx.x >> 1;
  int tid = threadIdx.x;
  int s = starts[c], e = starts[c + 1];
  int len = e - s;
  for (int j = tid; j < len; j += 256) lord[j] = order[s + j];
  __syncthreads();
  int f0 = (blockIdx.x & 1) * 1024 + tid * 4;
  float4 a = {0.f, 0.f, 0.f, 0.f};
  for (int i = 0; i < len; i++) {
    float4 v = *(const float4*)&xs[(size_t)lord[i] * F_DIM + f0];
    a.x += v.x; a.y += v.y; a.z += v.z; a.w += v.w;
  }
  *(float4*)&csum[(size_t)c * F_DIM + f0] = a;
}

// ---- K2: partial proto: grid = 64 classes x 2 d-halves x 8 f-chunks = 1024 blocks ----
__global__ __launch_bounds__(256) void k2_proto(const float* __restrict__ W,
                                               const float* __restrict__ csum,
                                               float* __restrict__ proto_acc) {
  __shared__ float cs[256];
  int bx = blockIdx.x;
  int c = bx >> 4;
  int dh = ((bx >> 3) & 1) * 256;
  int fc = (bx & 7) * 256;
  int tid = threadIdx.x;
  cs[tid] = csum[(size_t)c * F_DIM + fc + tid];
  __syncthreads();
  float a0 = 0.f;
#pragma unroll 8
  for (int f = 0; f < 256; f++)
    a0 += cs[f] * W[(size_t)(fc + f) * 512 + dh + tid];
  atomicAdd(&proto_acc[c * 512 + dh + tid], a0);
}

// ---- K2b: finalize proto: scale, +bias, bf16, per-128-slice pnorm_part[4][64] ----
__global__ __launch_bounds__(256) void k2b_finalize(const float* __restrict__ proto_acc,
                                                    const float* __restrict__ b,
                                                    const float* __restrict__ counts,
                                                    unsigned short* __restrict__ proto_bf,
                                                    float* __restrict__ pnorm_part) {
  __shared__ float red[256];
  int n = blockIdx.x, tid = threadIdx.x;
  float cntv = counts[n];
  float inv = 1.f / fmaxf(cntv, 1.f);
  float qsq[2];
#pragma unroll
  for (int h = 0; h < 2; h++) {
    int d = h * 256 + tid;
    float p = (proto_acc[n * 512 + d] + cntv * b[d]) * inv;
    unsigned short hh = f2bf(p);
    proto_bf[(size_t)n * 512 + d] = hh;
    float q = bf2f(hh);
    qsq[h] = q * q;
  }
#pragma unroll
  for (int h = 0; h < 2; h++) {
    __syncthreads();
    red[tid] = qsq[h];
    __syncthreads();
    for (int s = 64; s > 0; s >>= 1) {
      if ((tid & 127) < s) red[tid] += red[tid + s];
      __syncthreads();
    }
    if (tid == 0) pnorm_part[(h * 2 + 0) * 64 + n] = red[0];
    if (tid == 128) pnorm_part[(h * 2 + 1) * 64 + n] = red[128];
  }
}

// ---- K3 fused: z-tile GEMM (128x128, BK=64 as 2 panels of 128x32 halfs)
//      + fused distance epilogue (z->LDS, row-norms, S = z@proto^T, atomic out) ----
#define ZS_LD 136   // padded leading dim (halfs) for epilogue tiles
__global__ __launch_bounds__(256) void k3_fused(const float* __restrict__ xq,
                                                const unsigned short* __restrict__ Wt,
                                                const float* __restrict__ b,
                                                const unsigned short* __restrict__ proto_bf,
                                                const float* __restrict__ pnorm_part,
                                                float* __restrict__ out) {
  // union LDS: main loop lA(16K)+lB(16K); epilogue zs(34816)+pb(17408)+qnf(512)+pnl(256)
  __shared__ __align__(16) char smem[53248];
  unsigned short* lA = (unsigned short*)smem;           // 2 panels x (128 x 32 halfs)
  unsigned short* lB = (unsigned short*)(smem + 16384); // 2 panels x (128 x 32 halfs)
  unsigned short* zs = (unsigned short*)smem;
  unsigned short* pb = (unsigned short*)(smem + 34816);
  float* qnf = (float*)(smem + 52224);
  float* pnl = (float*)(smem + 52736);

  int tid = threadIdx.x;
  int bx = blockIdx.x;
  // XCD swizzle: 4 n-slices of one m-strip land on the same XCD (round-robin bx%8)
  int xcd = bx & 7;
  int g = bx >> 3;
  int m0 = (xcd * 16 + (g & 15)) * 128;
  int n0 = (g >> 4) * 128;
  int slice = g >> 4;

  int wave = tid >> 6, lane = tid & 63;
  int wm = (wave & 1) * 64, wn = (wave >> 1) * 64;
  int lrow = lane & 15, lquad = lane >> 4;

  floatx4 acc[4][4];
#pragma unroll
  for (int i = 0; i < 4; i++)
#pragma unroll
    for (int j = 0; j < 4; j++) acc[i][j] = (floatx4){0.f, 0.f, 0.f, 0.f};

  // A-staging: 4 chunks/thread; chunk ch = p*256+tid -> panel s=p>>1,
  // row = (p&1)*64 + (tid>>2), kq = tid&3. LDS addr = ch*16 B (lane-contiguous,
  // conflict-free b128 writes); global = 8 consecutive f32 (coalesced per 4 lanes).
  int arow = tid >> 2, akq = tid & 3;
  // B-staging via load_lds16: 4 calls; call i stages chunks i*256+wave*64+lane.
  int bch0 = wave * 64 + lane;

  for (int k0 = 0; k0 < F_DIM; k0 += 64) {
    // B: async global->LDS, panelized chunk map
#pragma unroll
    for (int i = 0; i < 4; i++) {
      int ch = i * 256 + bch0;
      int s = ch >> 9, row = (ch >> 2) & 127, kq = ch & 3;
      load_lds16(&Wt[(size_t)(n0 + row) * F_DIM + k0 + s * 32 + kq * 8],
                 &lB[(size_t)(i * 256 + wave * 64) * 8]);
    }
    // A: f32 global -> regs -> pack -> chunk-contiguous LDS writes
#pragma unroll
    for (int p = 0; p < 4; p++) {
      int s = p >> 1;
      int row = (p & 1) * 64 + arow;
      const float* gp = &xq[(size_t)(m0 + row) * F_DIM + k0 + s * 32 + akq * 8];
      float4 v0 = *(const float4*)gp;
      float4 v1 = *(const float4*)(gp + 4);
      uint4 w;
      w.x = pack_bf2(v0.x, v0.y); w.y = pack_bf2(v0.z, v0.w);
      w.z = pack_bf2(v1.x, v1.y); w.w = pack_bf2(v1.z, v1.w);
      *(uint4*)&lA[(size_t)(p * 256 + tid) * 8] = w;
    }
    __syncthreads();
#pragma unroll
    for (int s = 0; s < 2; s++) {
      short8 af[4], bfr[4];
#pragma unroll
      for (int i = 0; i < 4; i++)
        af[i] = *(const short8*)&lA[s * 4096 + (wm + i * 16 + lrow) * 32 + lquad * 8];
#pragma unroll
      for (int j = 0; j < 4; j++)
        bfr[j] = *(const short8*)&lB[s * 4096 + (wn + j * 16 + lrow) * 32 + lquad * 8];
#pragma unroll
      for (int i = 0; i < 4; i++)
#pragma unroll
        for (int j = 0; j < 4; j++)
          acc[i][j] = __builtin_amdgcn_mfma_f32_16x16x32_bf16(af[i], bfr[j], acc[i][j], 0, 0, 0);
    }
    __syncthreads();
  }

  // ---- epilogue phase 1: init qn, z -> LDS bf16, slice row-norms ----
  if (tid < 128) qnf[tid] = 0.f;
  if (tid < 64) pnl[tid] = pnorm_part[slice * 64 + tid];
  __syncthreads();

#pragma unroll
  for (int i = 0; i < 4; i++) {
    float rn[4] = {0.f, 0.f, 0.f, 0.f};
#pragma unroll
    for (int j = 0; j < 4; j++) {
      int ld = wn + j * 16 + lrow;          // local d (0..127)
      float bb = b[n0 + ld];
#pragma unroll
      for (int r = 0; r < 4; r++) {
        int rl = wm + i * 16 + lquad * 4 + r;  // local q (0..127)
        float v = acc[i][j][r] + bb;
        unsigned short h = f2bf(v);
        zs[rl * ZS_LD + ld] = h;
        float vq = bf2f(h);
        rn[r] += vq * vq;
      }
    }
#pragma unroll
    for (int r = 0; r < 4; r++) {
      float s = rn[r];
      s += __shfl_xor(s, 1, 16);
      s += __shfl_xor(s, 2, 16);
      s += __shfl_xor(s, 4, 16);
      s += __shfl_xor(s, 8, 16);
      if (lrow == 0) atomicAdd(&qnf[wm + i * 16 + lquad * 4 + r], s);
    }
  }

  // ---- phase 2: proto slice -> LDS (64 rows x 128 halfs, padded) ----
#pragma unroll
  for (int p = 0; p < 4; p++) {
    int ch = p * 256 + tid;
    int row = ch >> 4, l8 = (ch & 15) * 8;
    *(short8*)&pb[row * ZS_LD + l8] =
        *(const short8*)&proto_bf[(size_t)row * 512 + n0 + l8];
  }
  __syncthreads();

  // ---- phase 3: S = zs @ pb^T (128x64x128), out partial ----
  floatx4 acc2[2][4];
#pragma unroll
  for (int i = 0; i < 2; i++)
#pragma unroll
    for (int j = 0; j < 4; j++) acc2[i][j] = (floatx4){0.f, 0.f, 0.f, 0.f};

#pragma unroll
  for (int ks = 0; ks < 4; ks++) {
    short8 af2[2], bf2r[4];
#pragma unroll
    for (int i = 0; i < 2; i++)
      af2[i] = *(const short8*)&zs[(wave * 32 + i * 16 + lrow) * ZS_LD + ks * 32 + lquad * 8];
#pragma unroll
    for (int j = 0; j < 4; j++)
      bf2r[j] = *(const short8*)&pb[(j * 16 + lrow) * ZS_LD + ks * 32 + lquad * 8];
#pragma unroll
    for (int i = 0; i < 2; i++)
#pragma unroll
      for (int j = 0; j < 4; j++)
        acc2[i][j] = __builtin_amdgcn_mfma_f32_16x16x32_bf16(af2[i], bf2r[j], acc2[i][j], 0, 0, 0);
  }

#pragma unroll
  for (int i = 0; i < 2; i++) {
#pragma unroll
    for (int j = 0; j < 4; j++) {
      int c = j * 16 + lrow;
      float pn = pnl[c];
#pragma unroll
      for (int r = 0; r < 4; r++) {
        int ql = wave * 32 + i * 16 + lquad * 4 + r;
        float val = 2.f * acc2[i][j][r] - qnf[ql] - pn;
        atomicAdd(&out[(size_t)(m0 + ql) * 64 + c], val);
      }
    }
  }
}

extern "C" void kernel_launch(void* const* d_in, const int* in_sizes, int n_in,
                              void* d_out, int out_size, void* d_ws, size_t ws_size,
                              hipStream_t stream) {
  const float* xs = (const float*)d_in[0];
  const int* ys = (const int*)d_in[1];
  const float* xq = (const float*)d_in[2];
  const float* W = (const float*)d_in[3];
  const float* b = (const float*)d_in[4];
  float* out = (float*)d_out;
  char* ws = (char*)d_ws;

  size_t off = 0;
  auto take = [&](size_t bytes) -> char* {
    char* r = ws + off;
    off += (bytes + 255) & ~(size_t)255;
    return r;
  };
  unsigned short* Wt = (unsigned short*)take((size_t)D_DIM * F_DIM * 2);
  float* csum = (float*)take((size_t)NWAY * F_DIM * 4);
  float* proto_acc = (float*)take((size_t)NWAY * D_DIM * 4);
  unsigned short* proto_bf = (unsigned short*)take((size_t)NWAY * D_DIM * 2);
  float* counts = (float*)take(NWAY * 4);
  float* pnorm_part = (float*)take(4 * NWAY * 4);
  int* order = (int*)take(S_ROWS * 4);
  int* starts = (int*)take((NWAY + 1) * 4);

  k_prep<<<257, 256, 0, stream>>>(W, Wt, out, proto_acc, ys, order, starts, counts);
  k1_csum<<<128, 256, 0, stream>>>(xs, order, starts, csum);
  k2_proto<<<1024, 256, 0, stream>>>(W, csum, proto_acc);
  k2b_finalize<<<64, 256, 0, stream>>>(proto_acc, b, counts, proto_bf, pnorm_part);
  k3_fused<<<512, 256, 0, stream>>>(xq, Wt, b, proto_bf, pnorm_part, out);
}

// Round 7
// 266.760 us; speedup vs baseline: 1.1237x; 1.0185x over previous
//
#include <hip/hip_runtime.h>

// ProtoNet: out[q][n] = -|| (xq[q]@W + b) - proto[n] ||^2
// proto[n] = (sum_{s: ys==n} xs[s]) @ W / max(cnt,1) + cnt*b/max(cnt,1)
// Per-slice fusion: out[q][c] = sum_{slices s} (2*S_s[q][c] - qn_s[q] - pn_s[c])
// k3: 64x128 tile, 2-wave blocks (small barrier domains), grid 1024 = 4 blocks/CU.
// BK=64 (2 panels of 32), A packed in-register (round-half-up), B global_load_lds.

typedef __attribute__((ext_vector_type(8))) short short8;
typedef __attribute__((ext_vector_type(4))) float floatx4;

#define S_ROWS 1024
#define F_DIM  2048
#define D_DIM  512
#define NWAY   64
#define Q_ROWS 16384

static __device__ __forceinline__ unsigned short f2bf(float f) {
  unsigned int u = __float_as_uint(f);
  u += 0x7FFF + ((u >> 16) & 1);   // RNE
  return (unsigned short)(u >> 16);
}
static __device__ __forceinline__ float bf2f(unsigned short s) {
  return __uint_as_float(((unsigned int)s) << 16);
}
// pack two floats -> two bf16 (round-half-up; ties-only deviation from RNE)
static __device__ __forceinline__ unsigned int pack_bf2(float x, float y) {
  unsigned int ux = __float_as_uint(x) + 0x8000u;
  unsigned int uy = __float_as_uint(y) + 0x8000u;
  return __builtin_amdgcn_perm(uy, ux, 0x07060302u);  // hi16(uy)<<16 | hi16(ux)
}

// async global->LDS, 16B per lane. LDS dest = wave-uniform base + lane*16.
static __device__ __forceinline__ void load_lds16(const unsigned short* g, unsigned short* l) {
  __builtin_amdgcn_global_load_lds((const __attribute__((address_space(1))) unsigned int*)g,
                                   (__attribute__((address_space(3))) unsigned int*)l,
                                   16, 0, 0);
}

// ---- Kprep (257 blocks): blocks 0..255 transpose W f32 [2048][512] -> Wt bf16
//      [512][2048] + zero out/proto_acc; block 256 bins support ids by class ----
__global__ __launch_bounds__(256) void k_prep(const float* __restrict__ W,
                                              unsigned short* __restrict__ Wt,
                                              float* __restrict__ outz,
                                              float* __restrict__ proto_acc,
                                              const int* __restrict__ ys,
                                              int* __restrict__ order,
                                              int* __restrict__ starts,
                                              float* __restrict__ counts) {
  __shared__ unsigned short t[64][65];
  __shared__ int cnt[NWAY];
  __shared__ int st[NWAY + 1];
  __shared__ int wp[NWAY];
  int bx = blockIdx.x;
  int tid = threadIdx.x;
  if (bx < 256) {
    int f0 = (bx >> 3) << 6;   // 32 f-tiles
    int d0 = (bx & 7) << 6;    // 8 d-tiles
    for (int j = 0; j < 16; j++) {
      int lin = j * 256 + tid;
      int fl = lin >> 6, dl = lin & 63;
      t[fl][dl] = f2bf(W[(size_t)(f0 + fl) * 512 + d0 + dl]);
    }
    __syncthreads();
    for (int j = 0; j < 16; j++) {
      int lin = j * 256 + tid;
      int dl = lin >> 6, fl = lin & 63;
      Wt[(size_t)(d0 + dl) * 2048 + f0 + fl] = t[fl][dl];
    }
    float4 zz = {0.f, 0.f, 0.f, 0.f};
#pragma unroll
    for (int p = 0; p < 4; p++)
      *(float4*)&outz[(size_t)bx * 4096 + p * 1024 + tid * 4] = zz;
    if (tid < 128) proto_acc[bx * 128 + tid] = 0.f;
  } else {
    if (tid < NWAY) cnt[tid] = 0;
    __syncthreads();
    for (int j = tid; j < S_ROWS; j += 256) atomicAdd(&cnt[ys[j]], 1);
    __syncthreads();
    if (tid == 0) {
      int a = 0;
      for (int c = 0; c < NWAY; c++) { st[c] = a; wp[c] = a; a += cnt[c]; }
      st[NWAY] = a;
    }
    __syncthreads();
    for (int j = tid; j < S_ROWS; j += 256) {
      int c = ys[j];
      int p = atomicAdd(&wp[c], 1);
      order[p] = j;
    }
    if (tid < NWAY) counts[tid] = (float)cnt[tid];
    if (tid < NWAY + 1) starts[tid] = st[tid];
  }
}

// ---- K1: class sums. grid = 64 classes x 2 f-tiles; float4 per thread ----
__global__ __launch_bounds__(256) void k1_csum(const float* __restrict__ xs,
                                               const int* __restrict__ order,
                                               const int* __restrict__ starts,
                                               float* __restrict__ csum) {
  __shared__ int lord[S_ROWS];
  int c = blockIdx.x >> 1;
  int tid = threadIdx.x;
  int s = starts[c], e = starts[c + 1];
  int len = e - s;
  for (int j = tid; j < len; j += 256) lord[j] = order[s + j];
  __syncthreads();
  int f0 = (blockIdx.x & 1) * 1024 + tid * 4;
  float4 a = {0.f, 0.f, 0.f, 0.f};
  for (int i = 0; i < len; i++) {
    float4 v = *(const float4*)&xs[(size_t)lord[i] * F_DIM + f0];
    a.x += v.x; a.y += v.y; a.z += v.z; a.w += v.w;
  }
  *(float4*)&csum[(size_t)c * F_DIM + f0] = a;
}

// ---- K2: partial proto: grid = 64 classes x 2 d-halves x 8 f-chunks = 1024 blocks ----
__global__ __launch_bounds__(256) void k2_proto(const float* __restrict__ W,
                                               const float* __restrict__ csum,
                                               float* __restrict__ proto_acc) {
  __shared__ float cs[256];
  int bx = blockIdx.x;
  int c = bx >> 4;
  int dh = ((bx >> 3) & 1) * 256;
  int fc = (bx & 7) * 256;
  int tid = threadIdx.x;
  cs[tid] = csum[(size_t)c * F_DIM + fc + tid];
  __syncthreads();
  float a0 = 0.f;
#pragma unroll 8
  for (int f = 0; f < 256; f++)
    a0 += cs[f] * W[(size_t)(fc + f) * 512 + dh + tid];
  atomicAdd(&proto_acc[c * 512 + dh + tid], a0);
}

// ---- K2b: finalize proto: scale, +bias, bf16, per-128-slice pnorm_part[4][64] ----
__global__ __launch_bounds__(256) void k2b_finalize(const float* __restrict__ proto_acc,
                                                    const float* __restrict__ b,
                                                    const float* __restrict__ counts,
                                                    unsigned short* __restrict__ proto_bf,
                                                    float* __restrict__ pnorm_part) {
  __shared__ float red[256];
  int n = blockIdx.x, tid = threadIdx.x;
  float cntv = counts[n];
  float inv = 1.f / fmaxf(cntv, 1.f);
  float qsq[2];
#pragma unroll
  for (int h = 0; h < 2; h++) {
    int d = h * 256 + tid;
    float p = (proto_acc[n * 512 + d] + cntv * b[d]) * inv;
    unsigned short hh = f2bf(p);
    proto_bf[(size_t)n * 512 + d] = hh;
    float q = bf2f(hh);
    qsq[h] = q * q;
  }
#pragma unroll
  for (int h = 0; h < 2; h++) {
    __syncthreads();
    red[tid] = qsq[h];
    __syncthreads();
    for (int s = 64; s > 0; s >>= 1) {
      if ((tid & 127) < s) red[tid] += red[tid + s];
      __syncthreads();
    }
    if (tid == 0) pnorm_part[(h * 2 + 0) * 64 + n] = red[0];
    if (tid == 128) pnorm_part[(h * 2 + 1) * 64 + n] = red[128];
  }
}

// ---- K3 fused: 64x128 z-tile GEMM (2 waves, BK=64 as 2 panels of 32)
//      + fused distance epilogue. grid = 256 m-tiles x 4 n-slices = 1024 blocks. ----
#define ZS_LD 136   // padded leading dim (halfs) for epilogue tiles
__global__ __launch_bounds__(128) void k3_fused(const float* __restrict__ xq,
                                                const unsigned short* __restrict__ Wt,
                                                const float* __restrict__ b,
                                                const unsigned short* __restrict__ proto_bf,
                                                const float* __restrict__ pnorm_part,
                                                float* __restrict__ out) {
  // union LDS: main loop lA(8K)+lB(16K)=24K; epilogue zs(17408)+pb(17408)+qnf(256)+pnl(256)
  __shared__ __align__(16) char smem[35328];
  unsigned short* lA = (unsigned short*)smem;            // 2 panels x (64 x 32 halfs)
  unsigned short* lB = (unsigned short*)(smem + 8192);   // 2 panels x (128 x 32 halfs)
  unsigned short* zs = (unsigned short*)smem;            // 64 x ZS_LD
  unsigned short* pb = (unsigned short*)(smem + 17408);  // 64 x ZS_LD
  float* qnf = (float*)(smem + 34816);
  float* pnl = (float*)(smem + 35072);

  int tid = threadIdx.x;
  int bx = blockIdx.x;
  // XCD swizzle: the 4 n-slices of one m-strip land on the same XCD (bx%8 round-robin)
  int xcd = bx & 7;
  int g = bx >> 3;                 // 0..127
  int m0 = (xcd * 32 + (g & 31)) * 64;
  int n0 = (g >> 5) * 128;
  int slice = g >> 5;

  int wave = tid >> 6, lane = tid & 63;
  int wn = wave * 64;
  int lrow = lane & 15, lquad = lane >> 4;

  floatx4 acc[4][4];
#pragma unroll
  for (int i = 0; i < 4; i++)
#pragma unroll
    for (int j = 0; j < 4; j++) acc[i][j] = (floatx4){0.f, 0.f, 0.f, 0.f};

  // A: 4 chunks/thread. chunk ch=p*128+tid: panel s=p>>1, row=(p&1)*32+(tid>>2), kq=tid&3.
  int arow = tid >> 2, akq = tid & 3;
  const float* agp = &xq[(size_t)(m0 + arow) * F_DIM + akq * 8];
  // B: 8 chunks/thread via load_lds16. ch=i*128+tid: s=ch>>9, row=(ch>>2)&127, kq=ch&3.
  int bch0 = wave * 64 + lane;     // == tid

  for (int k0 = 0; k0 < F_DIM; k0 += 64) {
    // B: async global->LDS (issue first; DMA overlaps A's VGPR path)
#pragma unroll
    for (int i = 0; i < 8; i++) {
      int ch = i * 128 + bch0;
      int s = ch >> 9, row = (ch >> 2) & 127, kq = ch & 3;
      load_lds16(&Wt[(size_t)(n0 + row) * F_DIM + k0 + s * 32 + kq * 8],
                 &lB[(size_t)(i * 128 + wave * 64) * 8]);
    }
    // A: f32 global -> regs -> pack -> chunk-contiguous LDS writes
#pragma unroll
    for (int p = 0; p < 4; p++) {
      const float* gp = agp + (size_t)(p & 1) * 32 * F_DIM + (p >> 1) * 32 + k0;
      float4 v0 = *(const float4*)gp;
      float4 v1 = *(const float4*)(gp + 4);
      uint4 w;
      w.x = pack_bf2(v0.x, v0.y); w.y = pack_bf2(v0.z, v0.w);
      w.z = pack_bf2(v1.x, v1.y); w.w = pack_bf2(v1.z, v1.w);
      *(uint4*)&lA[(size_t)(p * 128 + tid) * 8] = w;
    }
    __syncthreads();
#pragma unroll
    for (int s = 0; s < 2; s++) {
      short8 af[4], bfr[4];
#pragma unroll
      for (int i = 0; i < 4; i++)
        af[i] = *(const short8*)&lA[s * 2048 + (i * 16 + lrow) * 32 + lquad * 8];
#pragma unroll
      for (int j = 0; j < 4; j++)
        bfr[j] = *(const short8*)&lB[s * 4096 + (wn + j * 16 + lrow) * 32 + lquad * 8];
#pragma unroll
      for (int i = 0; i < 4; i++)
#pragma unroll
        for (int j = 0; j < 4; j++)
          acc[i][j] = __builtin_amdgcn_mfma_f32_16x16x32_bf16(af[i], bfr[j], acc[i][j], 0, 0, 0);
    }
    __syncthreads();
  }

  // ---- epilogue phase 0: init qn, load pn ----
  if (tid < 64) { qnf[tid] = 0.f; pnl[tid] = pnorm_part[slice * 64 + tid]; }
  __syncthreads();

  // ---- phase 1: z -> LDS bf16 (64 x 128), slice row-norms via quad-shuffle + LDS atomics ----
#pragma unroll
  for (int i = 0; i < 4; i++) {
    float rn[4] = {0.f, 0.f, 0.f, 0.f};
#pragma unroll
    for (int j = 0; j < 4; j++) {
      int ld = wn + j * 16 + lrow;          // local d (0..127)
      float bb = b[n0 + ld];
#pragma unroll
      for (int r = 0; r < 4; r++) {
        int rl = i * 16 + lquad * 4 + r;    // local q (0..63)
        float v = acc[i][j][r] + bb;
        unsigned short h = f2bf(v);
        zs[rl * ZS_LD + ld] = h;
        float vq = bf2f(h);
        rn[r] += vq * vq;
      }
    }
#pragma unroll
    for (int r = 0; r < 4; r++) {
      float s = rn[r];
      s += __shfl_xor(s, 1, 16);
      s += __shfl_xor(s, 2, 16);
      s += __shfl_xor(s, 4, 16);
      s += __shfl_xor(s, 8, 16);
      if (lrow == 0) atomicAdd(&qnf[i * 16 + lquad * 4 + r], s);
    }
  }

  // ---- phase 2: proto slice -> LDS (64 rows x 128 halfs, padded) ----
#pragma unroll
  for (int p = 0; p < 8; p++) {
    int ch = p * 128 + tid;
    int row = ch >> 4, l8 = (ch & 15) * 8;
    *(short8*)&pb[row * ZS_LD + l8] =
        *(const short8*)&proto_bf[(size_t)row * 512 + n0 + l8];
  }
  __syncthreads();

  // ---- phase 3: S = zs @ pb^T (64x64x128); wave w does q-rows 32w..32w+31 ----
  floatx4 acc2[2][4];
#pragma unroll
  for (int i = 0; i < 2; i++)
#pragma unroll
    for (int j = 0; j < 4; j++) acc2[i][j] = (floatx4){0.f, 0.f, 0.f, 0.f};

#pragma unroll
  for (int ks = 0; ks < 4; ks++) {
    short8 af2[2], bf2r[4];
#pragma unroll
    for (int i = 0; i < 2; i++)
      af2[i] = *(const short8*)&zs[(wave * 32 + i * 16 + lrow) * ZS_LD + ks * 32 + lquad * 8];
#pragma unroll
    for (int j = 0; j < 4; j++)
      bf2r[j] = *(const short8*)&pb[(j * 16 + lrow) * ZS_LD + ks * 32 + lquad * 8];
#pragma unroll
    for (int i = 0; i < 2; i++)
#pragma unroll
      for (int j = 0; j < 4; j++)
        acc2[i][j] = __builtin_amdgcn_mfma_f32_16x16x32_bf16(af2[i], bf2r[j], acc2[i][j], 0, 0, 0);
  }

#pragma unroll
  for (int i = 0; i < 2; i++) {
#pragma unroll
    for (int j = 0; j < 4; j++) {
      int c = j * 16 + lrow;
      float pn = pnl[c];
#pragma unroll
      for (int r = 0; r < 4; r++) {
        int ql = wave * 32 + i * 16 + lquad * 4 + r;
        float val = 2.f * acc2[i][j][r] - qnf[ql] - pn;
        atomicAdd(&out[(size_t)(m0 + ql) * 64 + c], val);
      }
    }
  }
}

extern "C" void kernel_launch(void* const* d_in, const int* in_sizes, int n_in,
                              void* d_out, int out_size, void* d_ws, size_t ws_size,
                              hipStream_t stream) {
  const float* xs = (const float*)d_in[0];
  const int* ys = (const int*)d_in[1];
  const float* xq = (const float*)d_in[2];
  const float* W = (const float*)d_in[3];
  const float* b = (const float*)d_in[4];
  float* out = (float*)d_out;
  char* ws = (char*)d_ws;

  size_t off = 0;
  auto take = [&](size_t bytes) -> char* {
    char* r = ws + off;
    off += (bytes + 255) & ~(size_t)255;
    return r;
  };
  unsigned short* Wt = (unsigned short*)take((size_t)D_DIM * F_DIM * 2);
  float* csum = (float*)take((size_t)NWAY * F_DIM * 4);
  float* proto_acc = (float*)take((size_t)NWAY * D_DIM * 4);
  unsigned short* proto_bf = (unsigned short*)take((size_t)NWAY * D_DIM * 2);
  float* counts = (float*)take(NWAY * 4);
  float* pnorm_part = (float*)take(4 * NWAY * 4);
  int* order = (int*)take(S_ROWS * 4);
  int* starts = (int*)take((NWAY + 1) * 4);

  k_prep<<<257, 256, 0, stream>>>(W, Wt, out, proto_acc, ys, order, starts, counts);
  k1_csum<<<128, 256, 0, stream>>>(xs, order, starts, csum);
  k2_proto<<<1024, 256, 0, stream>>>(W, csum, proto_acc);
  k2b_finalize<<<64, 256, 0, stream>>>(proto_acc, b, counts, proto_bf, pnorm_part);
  k3_fused<<<1024, 128, 0, stream>>>(xq, Wt, b, proto_bf, pnorm_part, out);
}